// Round 2
// baseline (75201.080 us; speedup 1.0000x reference)
//
#include <hip/hip_runtime.h>
#include <cmath>

// Problem dims
#define B_  32
#define T_  512
#define D_  512
#define Q_  1024
#define G_  4096   // 4*Q
#define TC  32     // timestep chunk
#define NCHUNK (T_/TC)

// ---------------------------------------------------------------------------
__global__ void zero_kernel(float* __restrict__ p, int n) {
    int i = blockIdx.x * blockDim.x + threadIdx.x;
    if (i < n) p[i] = 0.f;
}

// ---------------------------------------------------------------------------
// pre[m, n] = sum_k A[row(m), k] * W[n, k] + bih[n] + bhh[n]
// m = b*TC + tt ; A row = b*TA + t0 + tt. W is [4096, K] row-major.
// pre is [B][TC][G]. BM=BN=128, BK=16, 256 threads, 8x8 micro-tile.
__global__ __launch_bounds__(256) void gemm_pre(
    const float* __restrict__ A, const float* __restrict__ W,
    const float* __restrict__ bih, const float* __restrict__ bhh,
    float* __restrict__ pre, int K, int TA, int t0)
{
    __shared__ __align__(16) float As[16][132];
    __shared__ __align__(16) float Bs[16][132];
    const int tid = threadIdx.x;
    const int tx = tid & 15, ty = tid >> 4;
    const int m0 = blockIdx.y * 128, n0 = blockIdx.x * 128;

    float acc[8][8];
#pragma unroll
    for (int i = 0; i < 8; ++i)
#pragma unroll
        for (int j = 0; j < 8; ++j) acc[i][j] = 0.f;

    for (int k0 = 0; k0 < K; k0 += 16) {
#pragma unroll
        for (int r = 0; r < 2; ++r) {
            int idx = tid + r * 256;
            int row = idx >> 2;
            int kq  = (idx & 3) << 2;
            int m = m0 + row;
            int bb = m >> 5, tt = m & 31;
            const float* ap = A + (size_t)(bb * TA + t0 + tt) * K + k0 + kq;
            float4 av = *(const float4*)ap;
            As[kq + 0][row] = av.x; As[kq + 1][row] = av.y;
            As[kq + 2][row] = av.z; As[kq + 3][row] = av.w;
            const float* wp = W + (size_t)(n0 + row) * K + k0 + kq;
            float4 wv = *(const float4*)wp;
            Bs[kq + 0][row] = wv.x; Bs[kq + 1][row] = wv.y;
            Bs[kq + 2][row] = wv.z; Bs[kq + 3][row] = wv.w;
        }
        __syncthreads();
#pragma unroll
        for (int k = 0; k < 16; ++k) {
            float a[8], bv[8];
#pragma unroll
            for (int i = 0; i < 8; ++i) a[i] = As[k][ty * 8 + i];
#pragma unroll
            for (int j = 0; j < 4; ++j) {
                bv[j]     = Bs[k][tx * 4 + j];
                bv[4 + j] = Bs[k][64 + tx * 4 + j];
            }
#pragma unroll
            for (int i = 0; i < 8; ++i)
#pragma unroll
                for (int j = 0; j < 8; ++j)
                    acc[i][j] = fmaf(a[i], bv[j], acc[i][j]);
        }
        __syncthreads();
    }

    const int n1 = n0 + tx * 4;
    const int n2 = n0 + 64 + tx * 4;
    float bias1[4], bias2[4];
#pragma unroll
    for (int j = 0; j < 4; ++j) {
        bias1[j] = bih[n1 + j] + bhh[n1 + j];
        bias2[j] = bih[n2 + j] + bhh[n2 + j];
    }
#pragma unroll
    for (int i = 0; i < 8; ++i) {
        int m = m0 + ty * 8 + i;
        float* prow = pre + (size_t)m * G_;
        float4 o1, o2;
        o1.x = acc[i][0] + bias1[0]; o1.y = acc[i][1] + bias1[1];
        o1.z = acc[i][2] + bias1[2]; o1.w = acc[i][3] + bias1[3];
        o2.x = acc[i][4] + bias2[0]; o2.y = acc[i][5] + bias2[1];
        o2.z = acc[i][6] + bias2[2]; o2.w = acc[i][7] + bias2[3];
        *(float4*)(prow + n1) = o1;
        *(float4*)(prow + n2) = o2;
    }
}

// ---------------------------------------------------------------------------
// Persistent chunk scan: one launch runs TC=32 LSTM steps for one layer.
// 256 WGs x 512 threads, exactly 1 WG/CU. WG wg owns q in [4*wg, 4*wg+4)
// (16 gate cols: col c = g*4+ql -> global gate row g*1024 + q0 + ql).
// Weights for those 16 cols live in REGISTERS (8 cols/wave x 16 k/lane =
// 128 VGPR/thread), loaded once per chunk. Per step: 8b x 8c register block
// per wave, K split across 64 lanes (k = lane*4 + j*256 + kk), h read
// coalesced from global (L2). In-wave butterfly (63 shuffles) reduces the
// k-partials so lane o holds output o (o = cc*8+bb). Cross-WG barrier:
// per-WG flags, release fence + atomic store / acquire polls.
__global__ __launch_bounds__(512, 2) void lstm_scan(
    const float* __restrict__ pre,   // [32][TC][4096], biases folded
    const float* __restrict__ whh,   // [4096][1024]
    float* __restrict__ h_a, float* __restrict__ h_b,   // [32][1024] x2
    float* __restrict__ c_st,        // [32][1024]
    float* __restrict__ yout, int yT, int yt0,
    int* __restrict__ flags, int flag_base)
{
    __shared__ float gbuf[16 * 33];
    const int tid  = threadIdx.x;
    const int lane = tid & 63;
    const int wave = tid >> 6;
    const int wg   = blockIdx.x;
    const int q0   = wg * 4;
    const int b0   = (wave & 3) * 8;
    const int c0   = (wave >> 2) * 8;

    // ---- load weight block into registers (lives across all 32 steps) ----
    float4 w4[8][4];
#pragma unroll
    for (int cc = 0; cc < 8; ++cc) {
        int c = c0 + cc;
        int grow = (c >> 2) * Q_ + q0 + (c & 3);
        const float* wrow = whh + (size_t)grow * Q_ + lane * 4;
#pragma unroll
        for (int j = 0; j < 4; ++j)
            w4[cc][j] = *(const float4*)(wrow + j * 256);
    }

    for (int tt = 0; tt < TC; ++tt) {
        const float* hc = (tt & 1) ? h_b : h_a;
        float*       hn = (tt & 1) ? h_a : h_b;

        float acc[64];
#pragma unroll
        for (int i = 0; i < 64; ++i) acc[i] = 0.f;

#pragma unroll
        for (int j = 0; j < 4; ++j) {
            float4 h4[8];
#pragma unroll
            for (int bb = 0; bb < 8; ++bb)
                h4[bb] = *(const float4*)(hc + (size_t)(b0 + bb) * Q_ + j * 256 + lane * 4);
#pragma unroll
            for (int cc = 0; cc < 8; ++cc)
#pragma unroll
                for (int bb = 0; bb < 8; ++bb) {
                    float s = acc[cc * 8 + bb];
                    s = fmaf(w4[cc][j].x, h4[bb].x, s);
                    s = fmaf(w4[cc][j].y, h4[bb].y, s);
                    s = fmaf(w4[cc][j].z, h4[bb].z, s);
                    s = fmaf(w4[cc][j].w, h4[bb].w, s);
                    acc[cc * 8 + bb] = s;
                }
        }

        // ---- butterfly reduce across lanes: lane o ends with output o ----
#define RED_ROUND(m, cnt)                                        \
        {                                                        \
            _Pragma("unroll")                                    \
            for (int i = 0; i < cnt; ++i) {                      \
                float a = acc[2 * i], b = acc[2 * i + 1];        \
                float keep = (lane & m) ? b : a;                 \
                float send = (lane & m) ? a : b;                 \
                acc[i] = keep + __shfl_xor(send, m, 64);         \
            }                                                    \
        }
        RED_ROUND(1, 32)
        RED_ROUND(2, 16)
        RED_ROUND(4, 8)
        RED_ROUND(8, 4)
        RED_ROUND(16, 2)
        RED_ROUND(32, 1)
#undef RED_ROUND

        // lane holds G[b0+(lane&7)][c0+(lane>>3)] (pre-activation, no pre yet)
        gbuf[(c0 + (lane >> 3)) * 33 + b0 + (lane & 7)] = acc[0];
        __syncthreads();

        // ---- finalize: 128 threads = (b, ql) ----
        if (tid < 128) {
            int b  = tid >> 2;
            int ql = tid & 3;
            int qi = q0 + ql;
            const float* prow = pre + ((size_t)(b * TC + tt)) * G_ + qi;
            float gi = gbuf[(0 * 4 + ql) * 33 + b] + prow[0];
            float gf = gbuf[(1 * 4 + ql) * 33 + b] + prow[1024];
            float gg = gbuf[(2 * 4 + ql) * 33 + b] + prow[2048];
            float go = gbuf[(3 * 4 + ql) * 33 + b] + prow[3072];
            float i_ = 1.f / (1.f + __expf(-gi));
            float f_ = 1.f / (1.f + __expf(-gf));
            float g_ = tanhf(gg);
            float o_ = 1.f / (1.f + __expf(-go));
            float c_old = c_st[b * Q_ + qi];
            float c_new = f_ * c_old + i_ * g_;
            float h_new = o_ * tanhf(c_new);
            c_st[b * Q_ + qi] = c_new;
            hn[b * Q_ + qi]   = h_new;
            yout[((size_t)b * yT + yt0 + tt) * Q_ + qi] = h_new;
        }

        // ---- release: make h_new visible device-wide, then raise flag ----
        __threadfence();          // per-wave wbl2 + vmcnt drain
        __syncthreads();
        const int tgt = flag_base + tt + 1;
        if (tid == 0)
            __hip_atomic_store(&flags[wg], tgt, __ATOMIC_RELEASE,
                               __HIP_MEMORY_SCOPE_AGENT);

        // ---- acquire: wave 0 polls all 256 flags ----
        if (wave == 0) {
            for (;;) {
                int f0 = __hip_atomic_load(&flags[lane],       __ATOMIC_ACQUIRE, __HIP_MEMORY_SCOPE_AGENT);
                int f1 = __hip_atomic_load(&flags[lane + 64],  __ATOMIC_ACQUIRE, __HIP_MEMORY_SCOPE_AGENT);
                int f2 = __hip_atomic_load(&flags[lane + 128], __ATOMIC_ACQUIRE, __HIP_MEMORY_SCOPE_AGENT);
                int f3 = __hip_atomic_load(&flags[lane + 192], __ATOMIC_ACQUIRE, __HIP_MEMORY_SCOPE_AGENT);
                int mn = min(min(f0, f1), min(f2, f3));
                if (__all(mn >= tgt)) break;
                __builtin_amdgcn_s_sleep(1);
            }
        }
        __syncthreads();
    }
}

// ---------------------------------------------------------------------------
__global__ void copy_hc(const float* __restrict__ h, const float* __restrict__ c,
                        float* __restrict__ dst)
{
    int i = blockIdx.x * blockDim.x + threadIdx.x;
    if (i < 32768) dst[i] = h[i];
    else           dst[i] = c[i - 32768];
}

// ---------------------------------------------------------------------------
extern "C" void kernel_launch(void* const* d_in, const int* in_sizes, int n_in,
                              void* d_out, int out_size, void* d_ws, size_t ws_size,
                              hipStream_t stream)
{
    const float* x    = (const float*)d_in[0];
    const float* wih0 = (const float*)d_in[1];
    const float* whh0 = (const float*)d_in[2];
    const float* bih0 = (const float*)d_in[3];
    const float* bhh0 = (const float*)d_in[4];
    const float* wih1 = (const float*)d_in[5];
    const float* whh1 = (const float*)d_in[6];
    const float* bih1 = (const float*)d_in[7];
    const float* bhh1 = (const float*)d_in[8];
    float* out = (float*)d_out;     // y1 [32,512,1024] ++ h[32,1024] ++ c[32,1024]
    float* ws  = (float*)d_ws;

    float* pre0 = ws;                  // 4,194,304 floats
    float* pre1 = ws + 4194304;        // 4,194,304
    float* y0c  = ws + 8388608;        // 1,048,576
    float* st   = ws + 9437184;        // 6 x 32768 state floats
    float* h0a = st;            float* h0b = st + 32768;
    float* c0  = st + 65536;
    float* h1a = st + 98304;    float* h1b = st + 131072;
    float* c1  = st + 163840;
    int*   flags = (int*)(ws + 9633792);   // 256 ints; total ws ~38.5 MB

    // zero states + flags (ws poisoned 0xAA before every call)
    hipLaunchKernelGGL(zero_kernel, dim3(769), dim3(256), 0, stream, st, 196864);

    int seq = 0;
    for (int ch = 0; ch < NCHUNK; ++ch) {
        const int t0 = ch * TC;
        hipLaunchKernelGGL(gemm_pre, dim3(32, 8), dim3(256), 0, stream,
                           x, wih0, bih0, bhh0, pre0, 512, 512, t0);
        hipLaunchKernelGGL(lstm_scan, dim3(256), dim3(512), 0, stream,
                           pre0, whh0, h0a, h0b, c0, y0c, TC, 0, flags, seq * TC);
        ++seq;
        hipLaunchKernelGGL(gemm_pre, dim3(32, 8), dim3(256), 0, stream,
                           y0c, wih1, bih1, bhh1, pre1, 1024, 32, 0);
        hipLaunchKernelGGL(lstm_scan, dim3(256), dim3(512), 0, stream,
                           pre1, whh1, h1a, h1b, c1, out, T_, t0, flags, seq * TC);
        ++seq;
    }
    // after 512 steps (even), final h/c live in the 'a' buffers
    hipLaunchKernelGGL(copy_hc, dim3(256), dim3(256), 0, stream,
                       h1a, c1, out + 16777216);
}